// Round 2
// baseline (328.916 us; speedup 1.0000x reference)
//
#include <hip/hip_runtime.h>
#include <math.h>

#define BB 4
#define NN 512
#define FIN 256
#define NH 8
#define FD 32
#define HF 256               // NH * FD
#define MASKV (-1000000.0f)
#define LOG2E 1.4426950408889634f
// leaky(x) = max(x, 0.21x) = CA*x + CB*|x|
#define CA 0.605f
#define CB 0.395f

// ---------------------------------------------------------------------------
// Kernel 1: dual GEMM  g = h @ W  (rows = B*N = 2048, K = 256, cols = 256).
// 8 rows/block, one W per blockIdx.y. h rows are wave-uniform -> scalar loads
// (K$), W column per thread -> coalesced vector loads. No LDS at all.
// ---------------------------------------------------------------------------
__global__ __launch_bounds__(256) void gemm_dual(
    const float* __restrict__ h, const float* __restrict__ Wl,
    const float* __restrict__ Wr, float* __restrict__ gl,
    float* __restrict__ gr) {
  const int t = threadIdx.x;
  const int row0 = blockIdx.x * 8;
  const float* __restrict__ W = blockIdx.y ? Wr : Wl;
  float* __restrict__ g = blockIdx.y ? gr : gl;

  float acc[8] = {0.f, 0.f, 0.f, 0.f, 0.f, 0.f, 0.f, 0.f};
  const float* Wp = W + t;                      // column t
  const float* hp = h + (size_t)row0 * FIN;     // uniform across lanes

#pragma unroll 2
  for (int k4 = 0; k4 < FIN / 4; ++k4) {
    float4 hv[8];
#pragma unroll
    for (int r = 0; r < 8; ++r)
      hv[r] = *(const float4*)(hp + r * FIN + 4 * k4);  // s_load_dwordx4
#pragma unroll
    for (int kk = 0; kk < 4; ++kk) {
      const float w = Wp[(size_t)(4 * k4 + kk) * HF];
#pragma unroll
      for (int r = 0; r < 8; ++r) {
        const float hval = (kk == 0) ? hv[r].x
                         : (kk == 1) ? hv[r].y
                         : (kk == 2) ? hv[r].z : hv[r].w;
        acc[r] = fmaf(hval, w, acc[r]);
      }
    }
  }

  float* gp = g + (size_t)row0 * HF + t;
#pragma unroll
  for (int r = 0; r < 8; ++r) gp[(size_t)r * HF] = acc[r];
}

// ---------------------------------------------------------------------------
// Kernel 2: fused GATv2 attention. Block = (head hh, 16-row i-tile, batch b).
// e[i,j] = CA*(Al[j] + Ar[i]) + sum_f (CB*w_f)*|gl[j,f] + gr[i,f]|
// pre-pass: Al_s[j] (per-block, from gl), a_s[ii] (from q_s)
// phase 1 : 2 VALU/element (v_add + v_fma with free abs modifier), no adj
// phase 2 : row softmax with adjacency mask applied reference-exactly
// phase 3 : out[ii,f] = (sum_j p[ii,j]*gr[j,f]) * inv_l[ii]
// ---------------------------------------------------------------------------
__global__ __launch_bounds__(256, 4) void gat_attn(
    const float* __restrict__ gl, const float* __restrict__ gr,
    const int* __restrict__ adj, const float* __restrict__ aw,
    float* __restrict__ out) {
  __shared__ float e_s[16][NN + 1];  // 32832 B, stride 513 floats
  __shared__ float Al_s[NN];         // CA * (w . gl[j,:])
  __shared__ float q_s[16][36];      // gr rows for this i-tile
  __shared__ float u_s[FD];          // CB * w
  __shared__ float w6_s[FD];         // CA * w
  __shared__ float a_s[16];          // CA * (w . gr[i,:])
  __shared__ float inv_l[16];

  const int t = threadIdx.x;
  const int hh = blockIdx.x;       // 0..7
  const int i0 = blockIdx.y * 16;  // i-tile
  const int b = blockIdx.z;        // 0..3

  if (t < FD) {
    const float w = aw[t];
    u_s[t] = CB * w;
    w6_s[t] = CA * w;
  }
  if (t < 128) {  // stage q (g_r rows of this i-tile): 16 x 32 floats
    const int ii = t >> 3, f4 = t & 7;
    *(float4*)&q_s[ii][f4 * 4] = *(const float4*)(
        gr + (size_t)(b * NN + i0 + ii) * HF + hh * FD + f4 * 4);
  }
  __syncthreads();

  // ---- pre-pass: Al_s[j] for all 512 j, a_s[ii] for the 16 rows ----
  {
    const float* glp = gl + (size_t)b * NN * HF + hh * FD;
#pragma unroll
    for (int c = 0; c < 2; ++c) {
      const int j = t + 256 * c;
      const float* p = glp + (size_t)j * HF;
      float s = 0.f;
#pragma unroll
      for (int f4 = 0; f4 < 8; ++f4) {
        const float4 g4 = *(const float4*)(p + 4 * f4);
        const float4 w4 = *(const float4*)&w6_s[4 * f4];
        s = fmaf(g4.x, w4.x, s);
        s = fmaf(g4.y, w4.y, s);
        s = fmaf(g4.z, w4.z, s);
        s = fmaf(g4.w, w4.w, s);
      }
      Al_s[j] = s;
    }
    if (t < 16) {
      float s = 0.f;
#pragma unroll
      for (int f = 0; f < FD; ++f) s = fmaf(q_s[t][f], w6_s[f], s);
      a_s[t] = s;
    }
  }
  __syncthreads();

  // ---- phase 1: scores (2 VALU per element) ----
  {
    const int ii = t & 15;           // query row in tile
    const int jl = t >> 4;           // 0..15, 32 j each
    const int xsw = (jl & 3) << 3;   // bank swizzle: 2-way max on e_s writes
    const int j0 = jl * 32;
    float qv[FD], uv[FD];
#pragma unroll
    for (int f4 = 0; f4 < 8; ++f4) {
      const float4 q4 = *(const float4*)&q_s[ii][f4 * 4];
      const float4 u4 = *(const float4*)&u_s[f4 * 4];
      qv[4 * f4 + 0] = q4.x; qv[4 * f4 + 1] = q4.y;
      qv[4 * f4 + 2] = q4.z; qv[4 * f4 + 3] = q4.w;
      uv[4 * f4 + 0] = u4.x; uv[4 * f4 + 1] = u4.y;
      uv[4 * f4 + 2] = u4.z; uv[4 * f4 + 3] = u4.w;
    }
    const float ar = a_s[ii];
    const float* glp = gl + (size_t)b * NN * HF + hh * FD;
#pragma unroll 2
    for (int jj = 0; jj < 32; ++jj) {
      const int j = j0 + (jj ^ xsw);
      const float* p = glp + (size_t)j * HF;
      float e0 = Al_s[j] + ar;
      float e1 = 0.f;
#pragma unroll
      for (int f4 = 0; f4 < 8; ++f4) {
        const float4 g4 = *(const float4*)(p + 4 * f4);
        // v_add_f32 + v_fma_f32 with abs() input modifier: 2 ops/element
        e0 = fmaf(uv[4 * f4 + 0], fabsf(g4.x + qv[4 * f4 + 0]), e0);
        e1 = fmaf(uv[4 * f4 + 1], fabsf(g4.y + qv[4 * f4 + 1]), e1);
        e0 = fmaf(uv[4 * f4 + 2], fabsf(g4.z + qv[4 * f4 + 2]), e0);
        e1 = fmaf(uv[4 * f4 + 3], fabsf(g4.w + qv[4 * f4 + 3]), e1);
      }
      e_s[ii][j] = e0 + e1;
    }
  }
  __syncthreads();

  // ---- phase 2: row softmax with reference-exact adjacency masking ----
  {
    const int lane = t & 63;
    const int row = (t >> 6) * 4 + (lane >> 4);  // 4 rows per wave
    const int l16 = lane & 15;                    // 16 lanes per row
    const int* adjp = adj + (size_t)(i0 + row) * NN + l16;
    int av[32];
#pragma unroll
    for (int c = 0; c < 32; ++c) av[c] = adjp[16 * c];
    float m = MASKV;
#pragma unroll
    for (int c = 0; c < 32; ++c) {
      const float v = av[c] ? e_s[row][l16 + 16 * c] : MASKV;
      m = fmaxf(m, v);
    }
#pragma unroll
    for (int off = 1; off < 16; off <<= 1) m = fmaxf(m, __shfl_xor(m, off));
    float s = 0.f;
#pragma unroll
    for (int c = 0; c < 32; ++c) {
      const float v = av[c] ? e_s[row][l16 + 16 * c] : MASKV;
      const float p = exp2f((v - m) * LOG2E);  // masked -> underflow to 0
      e_s[row][l16 + 16 * c] = p;
      s += p;
    }
#pragma unroll
    for (int off = 1; off < 16; off <<= 1) s += __shfl_xor(s, off);
    if (l16 == 0) inv_l[row] = 1.f / s;
  }
  __syncthreads();

  // ---- phase 3: aggregation ----
  {
    const int half = t >> 7;       // j-range split
    const int ii = (t >> 3) & 15;  // query row
    const int f4 = t & 7;          // feature quad
    const float* grp = gr + (size_t)b * NN * HF + hh * FD + f4 * 4;
    float4 acc = make_float4(0.f, 0.f, 0.f, 0.f);
    const int jb = half * 256;
#pragma unroll 4
    for (int j = jb; j < jb + 256; ++j) {
      const float p = e_s[ii][j];
      const float4 v = *(const float4*)(grp + (size_t)j * HF);
      acc.x = fmaf(p, v.x, acc.x);
      acc.y = fmaf(p, v.y, acc.y);
      acc.z = fmaf(p, v.z, acc.z);
      acc.w = fmaf(p, v.w, acc.w);
    }
    __syncthreads();
    if (half) *(float4*)&q_s[ii][f4 * 4] = acc;
    __syncthreads();
    if (!half) {
      const float4 o = *(const float4*)&q_s[ii][f4 * 4];
      const float sc = inv_l[ii];
      float4 r;
      r.x = (acc.x + o.x) * sc;
      r.y = (acc.y + o.y) * sc;
      r.z = (acc.z + o.z) * sc;
      r.w = (acc.w + o.w) * sc;
      *(float4*)(out + (size_t)(b * NN + i0 + ii) * HF + hh * FD + f4 * 4) = r;
    }
  }
}

// ---------------------------------------------------------------------------
extern "C" void kernel_launch(void* const* d_in, const int* in_sizes, int n_in,
                              void* d_out, int out_size, void* d_ws,
                              size_t ws_size, hipStream_t stream) {
  const float* h = (const float*)d_in[0];
  const int* adj = (const int*)d_in[1];
  const float* Wl = (const float*)d_in[2];
  const float* Wr = (const float*)d_in[3];
  const float* aw = (const float*)d_in[4];
  float* out = (float*)d_out;

  float* gl = (float*)d_ws;                // 2 MB
  float* gr = gl + (size_t)BB * NN * HF;   // 2 MB

  dim3 gg(BB * NN / 8, 2, 1);
  gemm_dual<<<gg, 256, 0, stream>>>(h, Wl, Wr, gl, gr);

  dim3 ga(NH, NN / 16, BB);
  gat_attn<<<ga, 256, 0, stream>>>(gl, gr, adj, aw, out);
}

// Round 3
// 164.326 us; speedup vs baseline: 2.0016x; 2.0016x over previous
//
#include <hip/hip_runtime.h>
#include <math.h>

#define BB 4
#define NN 512
#define FIN 256
#define NH 8
#define FD 32
#define HF 256               // NH * FD
#define MASKV (-1000000.0f)
// leaky(x) = max(x, 0.21x) = CA*x + CB*|x|
#define CA 0.605f
#define CB 0.395f

// ---------------------------------------------------------------------------
// Kernel 1: dual GEMM  g = h @ W  (rows = B*N = 2048, K = 256, cols = 256).
// 8 rows/block, one W per blockIdx.y. h rows wave-uniform -> scalar loads,
// W column per thread -> coalesced vector loads. No LDS.
// ---------------------------------------------------------------------------
__global__ __launch_bounds__(256) void gemm_dual(
    const float* __restrict__ h, const float* __restrict__ Wl,
    const float* __restrict__ Wr, float* __restrict__ gl,
    float* __restrict__ gr) {
  const int t = threadIdx.x;
  const int row0 = blockIdx.x * 8;
  const float* __restrict__ W = blockIdx.y ? Wr : Wl;
  float* __restrict__ g = blockIdx.y ? gr : gl;

  float acc[8] = {0.f, 0.f, 0.f, 0.f, 0.f, 0.f, 0.f, 0.f};
  const float* Wp = W + t;                      // column t
  const float* hp = h + (size_t)row0 * FIN;     // uniform across lanes

#pragma unroll 2
  for (int k4 = 0; k4 < FIN / 4; ++k4) {
    float4 hv[8];
#pragma unroll
    for (int r = 0; r < 8; ++r)
      hv[r] = *(const float4*)(hp + r * FIN + 4 * k4);
#pragma unroll
    for (int kk = 0; kk < 4; ++kk) {
      const float w = Wp[(size_t)(4 * k4 + kk) * HF];
#pragma unroll
      for (int r = 0; r < 8; ++r) {
        const float hval = (kk == 0) ? hv[r].x
                         : (kk == 1) ? hv[r].y
                         : (kk == 2) ? hv[r].z : hv[r].w;
        acc[r] = fmaf(hval, w, acc[r]);
      }
    }
  }

  float* gp = g + (size_t)row0 * HF + t;
#pragma unroll
  for (int r = 0; r < 8; ++r) gp[(size_t)r * HF] = acc[r];
}

// ---------------------------------------------------------------------------
// Kernel 2: fused GATv2 attention. Block = (head hh, 16-row i-tile, batch b).
// e[i,j] = CA*(Al[j] + Ar[i]) + sum_f (CB*w_f)*|gl[j,f] + gr[i,f]|
//   pre-pass: Al_s[j] = CA*(w.gl[j,:]), a_s[ii] = CA*(w.gr[i,:])
//   phase 1 : 2 VALU/element (v_add + v_fma with free abs modifier),
//             adjacency masked into e_s (round-1 semantics, no reg array)
//   phase 2 : row softmax, 16-lane shuffle reductions
//   phase 3 : out[ii,f] = (sum_j p[ii,j]*gr[j,f]) * inv_l[ii]
// NOTE: no __launch_bounds__ min-waves, no indexed reg arrays -> no spills
// (round-2 lesson: av[32]+(256,4) spilled ~700MB/dispatch to scratch).
// ---------------------------------------------------------------------------
__global__ __launch_bounds__(256) void gat_attn(
    const float* __restrict__ gl, const float* __restrict__ gr,
    const int* __restrict__ adj, const float* __restrict__ aw,
    float* __restrict__ out) {
  __shared__ float e_s[16][NN + 1];  // 32832 B, stride 513 floats
  __shared__ float Al_s[NN];         // CA * (w . gl[j,:])
  __shared__ float q_s[16][36];      // gr rows for this i-tile
  __shared__ float u_s[FD];          // CB * w
  __shared__ float w6_s[FD];         // CA * w
  __shared__ float a_s[16];          // CA * (w . gr[i,:])
  __shared__ float inv_l[16];

  const int t = threadIdx.x;
  const int hh = blockIdx.x;       // 0..7
  const int i0 = blockIdx.y * 16;  // i-tile
  const int b = blockIdx.z;        // 0..3

  if (t < FD) {
    const float w = aw[t];
    u_s[t] = CB * w;
    w6_s[t] = CA * w;
  }
  if (t < 128) {  // stage q (g_r rows of this i-tile): 16 x 32 floats
    const int ii = t >> 3, f4 = t & 7;
    *(float4*)&q_s[ii][f4 * 4] = *(const float4*)(
        gr + (size_t)(b * NN + i0 + ii) * HF + hh * FD + f4 * 4);
  }
  __syncthreads();

  // ---- pre-pass: Al_s[j] for all 512 j, a_s[ii] for the 16 rows ----
  {
    const float* glp = gl + (size_t)b * NN * HF + hh * FD;
#pragma unroll
    for (int c = 0; c < 2; ++c) {
      const int j = t + 256 * c;
      const float* p = glp + (size_t)j * HF;
      float s = 0.f;
#pragma unroll
      for (int f4 = 0; f4 < 8; ++f4) {
        const float4 g4 = *(const float4*)(p + 4 * f4);
        const float4 w4 = *(const float4*)&w6_s[4 * f4];
        s = fmaf(g4.x, w4.x, s);
        s = fmaf(g4.y, w4.y, s);
        s = fmaf(g4.z, w4.z, s);
        s = fmaf(g4.w, w4.w, s);
      }
      Al_s[j] = s;
    }
    if (t < 16) {
      float s = 0.f;
#pragma unroll
      for (int f = 0; f < FD; ++f) s = fmaf(q_s[t][f], w6_s[f], s);
      a_s[t] = s;
    }
  }
  __syncthreads();

  // ---- phase 1: scores (2 VALU/element) + adjacency mask ----
  {
    const int ii = t & 15;           // query row in tile
    const int jl = t >> 4;           // 0..15, 32 j each
    const int xsw = (jl & 3) << 3;   // e_s write bank swizzle -> conflict-free
    const int j0 = jl * 32;
    float qv[FD], uv[FD];
#pragma unroll
    for (int f4 = 0; f4 < 8; ++f4) {
      const float4 q4 = *(const float4*)&q_s[ii][f4 * 4];
      const float4 u4 = *(const float4*)&u_s[f4 * 4];
      qv[4 * f4 + 0] = q4.x; qv[4 * f4 + 1] = q4.y;
      qv[4 * f4 + 2] = q4.z; qv[4 * f4 + 3] = q4.w;
      uv[4 * f4 + 0] = u4.x; uv[4 * f4 + 1] = u4.y;
      uv[4 * f4 + 2] = u4.z; uv[4 * f4 + 3] = u4.w;
    }
    const float ar = a_s[ii];
    const float* glp = gl + (size_t)b * NN * HF + hh * FD;
    const int* adjp = adj + (size_t)(i0 + ii) * NN;
#pragma unroll 2
    for (int jj = 0; jj < 32; ++jj) {
      const int j = j0 + (jj ^ xsw);
      const float* p = glp + (size_t)j * HF;
      const int a = adjp[j];
      float e0 = Al_s[j] + ar;
      float e1 = 0.f;
#pragma unroll
      for (int f4 = 0; f4 < 8; ++f4) {
        const float4 g4 = *(const float4*)(p + 4 * f4);
        e0 = fmaf(uv[4 * f4 + 0], fabsf(g4.x + qv[4 * f4 + 0]), e0);
        e1 = fmaf(uv[4 * f4 + 1], fabsf(g4.y + qv[4 * f4 + 1]), e1);
        e0 = fmaf(uv[4 * f4 + 2], fabsf(g4.z + qv[4 * f4 + 2]), e0);
        e1 = fmaf(uv[4 * f4 + 3], fabsf(g4.w + qv[4 * f4 + 3]), e1);
      }
      e_s[ii][j] = a ? (e0 + e1) : MASKV;
    }
  }
  __syncthreads();

  // ---- phase 2: row softmax (masked entries hold MASKV -> exp underflows) --
  {
    const int lane = t & 63;
    const int row = (t >> 6) * 4 + (lane >> 4);  // 4 rows per wave
    const int l16 = lane & 15;                    // 16 lanes per row
    float m = MASKV;
#pragma unroll
    for (int c = 0; c < 32; ++c) m = fmaxf(m, e_s[row][l16 + 16 * c]);
#pragma unroll
    for (int off = 1; off < 16; off <<= 1) m = fmaxf(m, __shfl_xor(m, off));
    float s = 0.f;
#pragma unroll
    for (int c = 0; c < 32; ++c) {
      const float p = __expf(e_s[row][l16 + 16 * c] - m);
      e_s[row][l16 + 16 * c] = p;
      s += p;
    }
#pragma unroll
    for (int off = 1; off < 16; off <<= 1) s += __shfl_xor(s, off);
    if (l16 == 0) inv_l[row] = 1.f / s;
  }
  __syncthreads();

  // ---- phase 3: aggregation ----
  {
    const int half = t >> 7;       // j-range split
    const int ii = (t >> 3) & 15;  // query row
    const int f4 = t & 7;          // feature quad
    const float* grp = gr + (size_t)b * NN * HF + hh * FD + f4 * 4;
    float4 acc = make_float4(0.f, 0.f, 0.f, 0.f);
    const int jb = half * 256;
#pragma unroll 8
    for (int j = jb; j < jb + 256; ++j) {
      const float p = e_s[ii][j];
      const float4 v = *(const float4*)(grp + (size_t)j * HF);
      acc.x = fmaf(p, v.x, acc.x);
      acc.y = fmaf(p, v.y, acc.y);
      acc.z = fmaf(p, v.z, acc.z);
      acc.w = fmaf(p, v.w, acc.w);
    }
    __syncthreads();
    if (half) *(float4*)&q_s[ii][f4 * 4] = acc;
    __syncthreads();
    if (!half) {
      const float4 o = *(const float4*)&q_s[ii][f4 * 4];
      const float sc = inv_l[ii];
      float4 r;
      r.x = (acc.x + o.x) * sc;
      r.y = (acc.y + o.y) * sc;
      r.z = (acc.z + o.z) * sc;
      r.w = (acc.w + o.w) * sc;
      *(float4*)(out + (size_t)(b * NN + i0 + ii) * HF + hh * FD + f4 * 4) = r;
    }
  }
}

// ---------------------------------------------------------------------------
extern "C" void kernel_launch(void* const* d_in, const int* in_sizes, int n_in,
                              void* d_out, int out_size, void* d_ws,
                              size_t ws_size, hipStream_t stream) {
  const float* h = (const float*)d_in[0];
  const int* adj = (const int*)d_in[1];
  const float* Wl = (const float*)d_in[2];
  const float* Wr = (const float*)d_in[3];
  const float* aw = (const float*)d_in[4];
  float* out = (float*)d_out;

  float* gl = (float*)d_ws;                // 2 MB
  float* gr = gl + (size_t)BB * NN * HF;   // 2 MB

  dim3 gg(BB * NN / 8, 2, 1);
  gemm_dual<<<gg, 256, 0, stream>>>(h, Wl, Wr, gl, gr);

  dim3 ga(NH, NN / 16, BB);
  gat_attn<<<ga, 256, 0, stream>>>(gl, gr, adj, aw, out);
}

// Round 5
// 136.418 us; speedup vs baseline: 2.4111x; 1.2046x over previous
//
#include <hip/hip_runtime.h>
#include <math.h>

#define BB 4
#define NN 512
#define FIN 256
#define NH 8
#define FD 32
#define HF 256               // NH * FD
#define MASKV (-1000000.0f)
// leaky(x) = max(x, 0.21x) = CA*x + CB*|x|
#define CA 0.605f
#define CB 0.395f

typedef _Float16 h2_t __attribute__((ext_vector_type(2)));
union H2U { unsigned u; h2_t h; };

// cvt_pkrtz returns __fp16 vec2; bit-cast to our h2_t
__device__ __forceinline__ h2_t pkrtz(float a, float b) {
  auto r = __builtin_amdgcn_cvt_pkrtz(a, b);
  union { decltype(r) f; h2_t h; } u;
  u.f = r;
  return u.h;
}

// x = gl2 + q2 (v_pk_add_f16); |x| (v_and 0x7fff7fff); acc += u2 . |x| (v_dot2)
__device__ __forceinline__ float acc2(unsigned g, h2_t q, h2_t u, float acc) {
  H2U v; v.u = g;
  h2_t s = v.h + q;
  H2U a; a.h = s; a.u &= 0x7fff7fffu;
  return __builtin_amdgcn_fdot2(a.h, u, acc, false);
}

// ---------------------------------------------------------------------------
// Kernel 1: dual GEMM g = h @ W. blockIdx.y==0 -> gl in FP16 (phase-1 diet),
// y==1 -> gr in FP32 (phase-3 accuracy). h rows wave-uniform (s_load), W
// column per thread coalesced.
// ---------------------------------------------------------------------------
__global__ __launch_bounds__(256) void gemm_dual(
    const float* __restrict__ h, const float* __restrict__ Wl,
    const float* __restrict__ Wr, _Float16* __restrict__ glh,
    float* __restrict__ gr) {
  const int t = threadIdx.x;
  const int row0 = blockIdx.x * 8;
  const float* __restrict__ W = blockIdx.y ? Wr : Wl;

  float acc[8] = {0.f, 0.f, 0.f, 0.f, 0.f, 0.f, 0.f, 0.f};
  const float* Wp = W + t;
  const float* hp = h + (size_t)row0 * FIN;

#pragma unroll 2
  for (int k4 = 0; k4 < FIN / 4; ++k4) {
    float4 hv[8];
#pragma unroll
    for (int r = 0; r < 8; ++r)
      hv[r] = *(const float4*)(hp + r * FIN + 4 * k4);
#pragma unroll
    for (int kk = 0; kk < 4; ++kk) {
      const float w = Wp[(size_t)(4 * k4 + kk) * HF];
#pragma unroll
      for (int r = 0; r < 8; ++r) {
        const float hval = (kk == 0) ? hv[r].x
                         : (kk == 1) ? hv[r].y
                         : (kk == 2) ? hv[r].z : hv[r].w;
        acc[r] = fmaf(hval, w, acc[r]);
      }
    }
  }

  if (blockIdx.y == 0) {
    _Float16* gp = glh + (size_t)row0 * HF + t;
#pragma unroll
    for (int r = 0; r < 8; ++r) gp[(size_t)r * HF] = (_Float16)acc[r];
  } else {
    float* gp = gr + (size_t)row0 * HF + t;
#pragma unroll
    for (int r = 0; r < 8; ++r) gp[(size_t)r * HF] = acc[r];
  }
}

// ---------------------------------------------------------------------------
// Kernel 2: fused GATv2 attention. Block = (head hh, 16-row i-tile, batch b).
// e[i,j] = CA*(Al[j] + Ar[i]) + sum_f (CB*w_f)*|gl[j,f] + gr[i,f]|  (fp16 dot2)
// Lessons encoded: no __launch_bounds__ min-waves (R2 spill), adj as int4,
// phase-2 col map 32*(c>>1)|2*l16|(c&1) -> 2-way banks (free).
// ---------------------------------------------------------------------------
__global__ __launch_bounds__(256) void gat_attn(
    const _Float16* __restrict__ glh, const float* __restrict__ gr,
    const int* __restrict__ adj, const float* __restrict__ aw,
    float* __restrict__ out) {
  __shared__ float e_s[16][NN + 1];  // stride 513 floats
  __shared__ float Al_s[NN];         // CA * (w . gl[j,:])
  __shared__ float q_s[16][36];      // gr rows (fp32) for this i-tile
  __shared__ float w6_s[FD];         // CA * w (fp32)
  __shared__ unsigned uh_s[16];      // CB * w packed fp16
  __shared__ unsigned w6h_s[16];     // CA * w packed fp16
  __shared__ float a_s[16];          // CA * (w . gr[i,:])
  __shared__ float inv_l[16];

  const int t = threadIdx.x;
  const int hh = blockIdx.x;
  const int i0 = blockIdx.y * 16;
  const int b = blockIdx.z;

  if (t < FD) w6_s[t] = CA * aw[t];
  if (t < 16) {
    const float w0 = aw[2 * t], w1 = aw[2 * t + 1];
    H2U p0; p0.h = pkrtz(CB * w0, CB * w1);
    uh_s[t] = p0.u;
    H2U p1; p1.h = pkrtz(CA * w0, CA * w1);
    w6h_s[t] = p1.u;
  }
  if (t < 128) {  // stage q (g_r fp32 rows of this i-tile): 16 x 32 floats
    const int ii = t >> 3, f4 = t & 7;
    *(float4*)&q_s[ii][f4 * 4] = *(const float4*)(
        gr + (size_t)(b * NN + i0 + ii) * HF + hh * FD + f4 * 4);
  }
  __syncthreads();

  const _Float16* glp = glh + (size_t)b * NN * HF + hh * FD;

  // ---- pre-pass: Al_s[j] (fp16 dot2), a_s[ii] (fp32) ----
  {
    h2_t wv[16];
#pragma unroll
    for (int f2 = 0; f2 < 16; ++f2) { H2U v; v.u = w6h_s[f2]; wv[f2] = v.h; }
#pragma unroll
    for (int c = 0; c < 2; ++c) {
      const int j = t + 256 * c;
      const uint4* gp = (const uint4*)(glp + (size_t)j * HF);
      const uint4 g0 = gp[0], g1 = gp[1], g2 = gp[2], g3 = gp[3];
      float s0 = 0.f, s1 = 0.f;
      H2U v;
#define ALD(gu, i)                                              \
  v.u = gu.x; s0 = __builtin_amdgcn_fdot2(v.h, wv[i+0], s0, false); \
  v.u = gu.y; s1 = __builtin_amdgcn_fdot2(v.h, wv[i+1], s1, false); \
  v.u = gu.z; s0 = __builtin_amdgcn_fdot2(v.h, wv[i+2], s0, false); \
  v.u = gu.w; s1 = __builtin_amdgcn_fdot2(v.h, wv[i+3], s1, false);
      ALD(g0, 0) ALD(g1, 4) ALD(g2, 8) ALD(g3, 12)
#undef ALD
      Al_s[j] = s0 + s1;
    }
    if (t < 16) {
      float s = 0.f;
#pragma unroll
      for (int f = 0; f < FD; ++f) s = fmaf(q_s[t][f], w6_s[f], s);
      a_s[t] = s;
    }
  }
  __syncthreads();

  // ---- phase 1: scores, 3 VALU per 2 elements ----
  {
    const int ii = t & 15;          // query row
    const int jl = t >> 4;          // 0..15, 32 j each
    const int xsw = (jl & 3) << 3;  // write-bank swizzle -> 2-way (free)
    const int j0 = jl * 32;
    h2_t qh[16], uh[16];
#pragma unroll
    for (int f2 = 0; f2 < 16; ++f2) {
      const float2 q2 = *(const float2*)&q_s[ii][2 * f2];
      qh[f2] = pkrtz(q2.x, q2.y);
      H2U v; v.u = uh_s[f2]; uh[f2] = v.h;
    }
    const float ar = a_s[ii];
    const int* adjp = adj + (size_t)(i0 + ii) * NN + j0;
#pragma unroll 2
    for (int jg = 0; jg < 8; ++jg) {
      const int jq = (jg * 4) ^ xsw;
      const int4 a4 = *(const int4*)(adjp + jq);
#define DO_J(K, AV)                                                        \
  {                                                                        \
    const int j = j0 + jq + K;                                             \
    const uint4* gp = (const uint4*)(glp + (size_t)j * HF);                \
    const uint4 g0 = gp[0], g1 = gp[1], g2 = gp[2], g3 = gp[3];            \
    float e0 = Al_s[j] + ar, e1 = 0.f;                                     \
    e0 = acc2(g0.x, qh[0], uh[0], e0);                                     \
    e1 = acc2(g0.y, qh[1], uh[1], e1);                                     \
    e0 = acc2(g0.z, qh[2], uh[2], e0);                                     \
    e1 = acc2(g0.w, qh[3], uh[3], e1);                                     \
    e0 = acc2(g1.x, qh[4], uh[4], e0);                                     \
    e1 = acc2(g1.y, qh[5], uh[5], e1);                                     \
    e0 = acc2(g1.z, qh[6], uh[6], e0);                                     \
    e1 = acc2(g1.w, qh[7], uh[7], e1);                                     \
    e0 = acc2(g2.x, qh[8], uh[8], e0);                                     \
    e1 = acc2(g2.y, qh[9], uh[9], e1);                                     \
    e0 = acc2(g2.z, qh[10], uh[10], e0);                                   \
    e1 = acc2(g2.w, qh[11], uh[11], e1);                                   \
    e0 = acc2(g3.x, qh[12], uh[12], e0);                                   \
    e1 = acc2(g3.y, qh[13], uh[13], e1);                                   \
    e0 = acc2(g3.z, qh[14], uh[14], e0);                                   \
    e1 = acc2(g3.w, qh[15], uh[15], e1);                                   \
    e_s[ii][j] = AV ? (e0 + e1) : MASKV;                                   \
  }
      DO_J(0, a4.x) DO_J(1, a4.y) DO_J(2, a4.z) DO_J(3, a4.w)
#undef DO_J
    }
  }
  __syncthreads();

  // ---- phase 2: row softmax; col map keeps banks 2-way (free) ----
  {
    const int lane = t & 63;
    const int row = ((t >> 6) << 2) + (lane >> 4);
    const int l16 = lane & 15;
    const int cb = 2 * l16;
    float m = MASKV;
#pragma unroll
    for (int c = 0; c < 32; ++c) {
      const int col = ((c >> 1) << 5) | cb | (c & 1);
      m = fmaxf(m, e_s[row][col]);
    }
#pragma unroll
    for (int off = 1; off < 16; off <<= 1) m = fmaxf(m, __shfl_xor(m, off));
    float s = 0.f;
#pragma unroll
    for (int c = 0; c < 32; ++c) {
      const int col = ((c >> 1) << 5) | cb | (c & 1);
      const float p = __expf(e_s[row][col] - m);
      e_s[row][col] = p;
      s += p;
    }
#pragma unroll
    for (int off = 1; off < 16; off <<= 1) s += __shfl_xor(s, off);
    if (l16 == 0) inv_l[row] = 1.f / s;
  }
  __syncthreads();

  // ---- phase 3: aggregation (fp32 gr) ----
  {
    const int half = t >> 7;
    const int ii = (t >> 3) & 15;
    const int f4 = t & 7;
    const float* grp = gr + (size_t)b * NN * HF + hh * FD + f4 * 4;
    float4 acc = make_float4(0.f, 0.f, 0.f, 0.f);
    const int jb = half * 256;
#pragma unroll 8
    for (int j = jb; j < jb + 256; ++j) {
      const float p = e_s[ii][j];
      const float4 v = *(const float4*)(grp + (size_t)j * HF);
      acc.x = fmaf(p, v.x, acc.x);
      acc.y = fmaf(p, v.y, acc.y);
      acc.z = fmaf(p, v.z, acc.z);
      acc.w = fmaf(p, v.w, acc.w);
    }
    __syncthreads();
    if (half) *(float4*)&q_s[ii][f4 * 4] = acc;
    __syncthreads();
    if (!half) {
      const float4 o = *(const float4*)&q_s[ii][f4 * 4];
      const float sc = inv_l[ii];
      float4 r;
      r.x = (acc.x + o.x) * sc;
      r.y = (acc.y + o.y) * sc;
      r.z = (acc.z + o.z) * sc;
      r.w = (acc.w + o.w) * sc;
      *(float4*)(out + (size_t)(b * NN + i0 + ii) * HF + hh * FD + f4 * 4) = r;
    }
  }
}

// ---------------------------------------------------------------------------
extern "C" void kernel_launch(void* const* d_in, const int* in_sizes, int n_in,
                              void* d_out, int out_size, void* d_ws,
                              size_t ws_size, hipStream_t stream) {
  const float* h = (const float*)d_in[0];
  const int* adj = (const int*)d_in[1];
  const float* Wl = (const float*)d_in[2];
  const float* Wr = (const float*)d_in[3];
  const float* aw = (const float*)d_in[4];
  float* out = (float*)d_out;

  _Float16* glh = (_Float16*)d_ws;                         // 1 MB fp16
  float* gr = (float*)((char*)d_ws + (size_t)BB * NN * HF * 2);  // 2 MB fp32

  dim3 gg(BB * NN / 8, 2, 1);
  gemm_dual<<<gg, 256, 0, stream>>>(h, Wl, Wr, glh, gr);

  dim3 ga(NH, NN / 16, BB);
  gat_attn<<<ga, 256, 0, stream>>>(glh, gr, adj, aw, out);
}